// Round 3
// baseline (6199.836 us; speedup 1.0000x reference)
//
#include <hip/hip_runtime.h>
#include <cstdint>

// mLstm  B=16, P=128, Q=256, D=128, H=128. fp32 in/out.
// R8: fit-under-64-VGPR redesign (R6/R7 post-mortem: both residency attempts
// spilled: VGPR stuck at 64, WRITE_SIZE showed 14MB spill-init). Now only wE
// (32f) is register-resident; A streams WrT (loads issued at loop top, hidden
// under h-stage); B reads whs from LDS + inline exp-tanh (tA buffer deleted).
// 8 blocks/batch (128 blocks, cooperative): only F(512x384 GEMV)+cell split ->
// ONE global barrier per step (scores stay local). Prologue fused to 4 launches.

__device__ __forceinline__ float bf2f(uint16_t u) {
  uint32_t x = ((uint32_t)u) << 16; float f; __builtin_memcpy(&f, &x, 4); return f;
}
__device__ __forceinline__ float load_in(const void* p, size_t i, int f32) {
  return f32 ? ((const float*)p)[i] : bf2f(((const uint16_t*)p)[i]);
}
__device__ __forceinline__ float frcp(float x) { return __builtin_amdgcn_rcpf(x); }
__device__ __forceinline__ float tanh_fast(float x) {
  float E = __expf(2.0f * x);            // saturates correctly at +/-inf
  return 1.0f - 2.0f * frcp(E + 1.0f);
}
__device__ __forceinline__ float sigm(float x) {
  return frcp(1.0f + __expf(-x));
}
__device__ __forceinline__ void st_agent(float* p, float v) {
  __hip_atomic_store(p, v, __ATOMIC_RELAXED, __HIP_MEMORY_SCOPE_AGENT);
}
__device__ __forceinline__ float ld_agent(const float* p) {
  return __hip_atomic_load(p, __ATOMIC_RELAXED, __HIP_MEMORY_SCOPE_AGENT);
}

// ------------------------------------------------------------- detect kernel
__global__ void detect_kernel(const uint16_t* __restrict__ q16,
                              uint32_t* __restrict__ flag) {
  __shared__ int cnt;
  if (threadIdx.x == 0) cnt = 0;
  __syncthreads();
  int bad = 0;
  for (int i = threadIdx.x; i < 4096; i += 256) {
    int e = (q16[i] >> 7) & 0xFF;
    if (e > 0x8A) bad++;
  }
  atomicAdd(&cnt, bad);
  __syncthreads();
  if (threadIdx.x == 0) *flag = (cnt > 16) ? 1u : 0u;
}

// ------------------------------------------------- convert + transpose pack
// pf[262144]=p; WrT2[j*128+k]=Wr[j][k] (plain copy/convert); wrb;wew;web;
// WgT[k*256+i]=Wg[i][k] for k<128 (32768); WTp k4-major float4 pack
// WTp[k4*2048+i*4+c]=WT[k4*4+c][i], WT[k]=k<256?Wih[:,k]:Whh[:,k-256];
// bb=bih+bhh; zero h_ex[4096]; zero ctr[2048].
__global__ void pack2(const void* __restrict__ p,
                      const void* __restrict__ Wr,  const void* __restrict__ Wrb_,
                      const void* __restrict__ Wew_, const void* __restrict__ Web_,
                      const void* __restrict__ Wg,
                      const void* __restrict__ Wih, const void* __restrict__ Whh,
                      const void* __restrict__ bih, const void* __restrict__ bhh,
                      float* __restrict__ pf,
                      float* __restrict__ WrT2, float* __restrict__ wrb,
                      float* __restrict__ wew, float* __restrict__ web,
                      float* __restrict__ WgT,
                      float* __restrict__ WTp, float* __restrict__ bb,
                      const uint32_t* __restrict__ flag,
                      float* __restrict__ hexz, uint32_t* __restrict__ ctrz) {
  const int f32 = (int)*flag;
  long idx = (long)blockIdx.x * blockDim.x + threadIdx.x;
  if (idx < 262144) { pf[idx] = load_in(p, idx, f32); return; }
  idx -= 262144;
  if (idx < 16384) { WrT2[idx] = load_in(Wr, idx, f32); return; }
  idx -= 16384;
  if (idx < 128) { wrb[idx] = load_in(Wrb_, idx, f32); return; }
  idx -= 128;
  if (idx < 128) { wew[idx] = load_in(Wew_, idx, f32); return; }
  idx -= 128;
  if (idx < 1) { web[0] = load_in(Web_, 0, f32); return; }
  idx -= 1;
  if (idx < 32768) { int k = idx >> 8, i = idx & 255;
    WgT[idx] = load_in(Wg, (size_t)i * 256 + k, f32); return; }
  idx -= 32768;
  if (idx < 196608) {
    int k4 = idx >> 11, i = (idx >> 2) & 511, c = idx & 3;
    int k = k4 * 4 + c;
    WTp[idx] = (k < 256) ? load_in(Wih, (size_t)i * 256 + k, f32)
                         : load_in(Whh, (size_t)i * 128 + (k - 256), f32);
    return; }
  idx -= 196608;
  if (idx < 512) { bb[idx] = load_in(bih, idx, f32) + load_in(bhh, idx, f32); return; }
  idx -= 512;
  if (idx < 4096) { hexz[idx] = 0.f; return; }
  idx -= 4096;
  if (idx < 2048) { ctrz[idx] = 0u; return; }
}

// --------------------------------------------- fused 3-way small GEMM (K=128)
// blocks [0,256): whs = q@Ws^T+b  [4096x128]
// blocks [256,384): wht = p@Wt^T+b [2048x128]
// blocks [384,512): Gp = p@Wg[:,128:]^T+b [2048x256]
__global__ __launch_bounds__(256) void gemm3(
    const void* __restrict__ q, const void* __restrict__ p,
    const void* __restrict__ Wsw, const void* __restrict__ Wsb,
    const void* __restrict__ Wtw, const void* __restrict__ Wtb,
    const void* __restrict__ Wgw, const void* __restrict__ Wgb,
    float* __restrict__ whs, float* __restrict__ wht, float* __restrict__ Gp,
    const uint32_t* __restrict__ flag) {
  __shared__ float A_l[16][128];
  __shared__ float W_l[64][129];
  const int f32 = (int)*flag;
  const int t = threadIdx.x;
  const void* A; const void* W; const void* bias; float* out;
  int lda = 128, ldw, w_off, C, r0;
  int blk = blockIdx.x;
  if (blk < 256)      { A = q; W = Wsw; bias = Wsb; out = whs; ldw = 128; w_off = 0;   C = 128; r0 = blk * 16; }
  else if (blk < 384) { A = p; W = Wtw; bias = Wtb; out = wht; ldw = 128; w_off = 0;   C = 128; r0 = (blk - 256) * 16; }
  else                { A = p; W = Wgw; bias = Wgb; out = Gp;  ldw = 256; w_off = 128; C = 256; r0 = (blk - 384) * 16; }
  for (int idx = t; idx < 16 * 128; idx += 256) {
    int rr = idx >> 7, kk = idx & 127;
    A_l[rr][kk] = load_in(A, (size_t)(r0 + rr) * lda + kk, f32);
  }
  const int c_l = t & 63, rg = t >> 6;
  for (int c0 = 0; c0 < C; c0 += 64) {
    __syncthreads();
    for (int idx = t; idx < 64 * 128; idx += 256) {
      int cc = idx >> 7, kk = idx & 127;
      W_l[cc][kk] = load_in(W, (size_t)w_off + (size_t)(c0 + cc) * ldw + kk, f32);
    }
    __syncthreads();
    float acc[4] = {0.f, 0.f, 0.f, 0.f};
    for (int k = 0; k < 128; k++) {
      float w = W_l[c_l][k];
#pragma unroll
      for (int x = 0; x < 4; x++) acc[x] = fmaf(A_l[rg * 4 + x][k], w, acc[x]);
    }
    float bv = load_in(bias, c0 + c_l, f32);
#pragma unroll
    for (int x = 0; x < 4; x++)
      out[(size_t)(r0 + rg * 4 + x) * C + c0 + c_l] = acc[x] + bv;
  }
}

// ---------------------------------------------------------- sequential kernel
// 128 blocks x 1024 threads; group = batch b = blockIdx&15, slice kblk =
// blockIdx>>4 (8 per batch). Only F (gates GEMV) + cell are split; one global
// barrier per step (h exchange, parity double-buffered).
#define TUIDX(j) ((((j) >> 5) * 36) + ((j) & 31))
#define SCIDX(q) ((((q) >> 5) * 36) + ((q) & 31))
#define AIDX(h)  ((((h) >> 5) * 36) + ((h) & 31))
#define HIDX(k)  ((((k) >> 4) * 20) + ((k) & 15))
#define XIDX(i)  ((((i) / 24) * 28) + ((i) % 24))

__global__ __launch_bounds__(1024) void mlstm_seq6(
    const float* __restrict__ pf,    // [16][128][128]
    const float* __restrict__ whs,   // [16][256][128]
    const float* __restrict__ wht_g, // [16][128][128]
    const float* __restrict__ Gp_g,  // [16][128][256]
    const float* __restrict__ WrT2,  // [128][128] j-major (== Wr layout)
    const float* __restrict__ wrb,   // [128]
    const float* __restrict__ wew,   // [128]
    const float* __restrict__ web,   // [1]
    const float* __restrict__ WgT,   // [128][256] k-major
    const float* __restrict__ WTp,   // [96][512][4] k4-major float4 pack
    const float* __restrict__ bb,    // [512]
    float* __restrict__ h_ex,        // [2][16][128] parity exchange
    uint32_t* __restrict__ ctr,      // [16][128] barrier counters
    float* __restrict__ out) {       // [16][128][128]
  const int b = blockIdx.x & 15, kblk = blockIdx.x >> 4, t = threadIdx.x;

  __shared__ __align__(16) float whs_l[256 * 132];   // rows padded to 132
  __shared__ __align__(16) float tu_s[144];
  __shared__ __align__(16) float wew_s[144];
  __shared__ __align__(16) float sc_s[288];
  __shared__ __align__(16) float alpha_s[144];
  __shared__ __align__(16) float xh_s[448];          // 16 chunks x 28 (24 used)
  __shared__ __align__(16) float h_s[160];
  __shared__ __align__(16) float gates_s[64];

  const float* whs_b = whs + (size_t)b * 32768;

  // thread mappings (reduction groups = consecutive lanes -> shfl)
  const int jA = t >> 3, kgA = t & 7;     // A: 128 j x 8 kg (16 k)
  const int qB = t >> 2, hgB = t & 3;     // B: 256 q x 4 hg (32 h)
  const int hD = t >> 3, qgD = t & 7;     // D: 128 h x 8 qg (32 q interleaved)
  const int iE = t >> 2, kgE = t & 3;     // E: 256 i x 4 kg (32 k)
  const int iF = t >> 4, kgF = t & 15;    // F: 64 rows x 16 kg (24 k)
  const int rowF = ((iF >> 4) << 7) + (kblk << 4) + (iF & 15);

  // ---- LDS init: whs (float4, padded rows: 132*4B = 16B-aligned)
  for (int i4 = t; i4 < 8192; i4 += 1024)
    *(float4*)(whs_l + (i4 >> 5) * 132 + ((i4 & 31) << 2)) =
        *(const float4*)(whs_b + ((size_t)i4 << 2));
  if (t < 128) wew_s[TUIDX(t)] = wew[t];

  // ---- ONLY register residency: wE (32 floats) -> total demand < 64 VGPR
  float wE[32];
#pragma unroll
  for (int r = 0; r < 32; r++)
    wE[r] = WgT[(size_t)(kgE * 32 + r) * 256 + iE];

  const float web_r = web[0];
  const float wrb_r = wrb[jA];
  const float bbF_r = bb[rowF];
  float c_r = 0.f;                        // t<16 owners

  const float* wr_p = WrT2 + (size_t)jA * 128 + kgA * 16;  // A weights (stream)
  const int aIdxE = AIDX(iE & 127);
  const int xIdxE = XIDX(iE);
  const int xIdxH = (t < 128) ? XIDX(256 + t) : 0;
  uint32_t* ctr_b = ctr + b * 128;

  // per-step prefetch registers
  float wht_c = (kgA == 0) ? wht_g[((size_t)b * 128 + 0) * 128 + jA] : 0.f;
  float gp_c  = (kgE == 0) ? Gp_g[((size_t)b * 128 + 0) * 256 + iE] : 0.f;
  float pf_c  = (kgE == 0 && iE >= 128) ? pf[((size_t)b * 128 + 0) * 128 + (iE - 128)] : 0.f;

  __syncthreads();

  for (int st = 0; st < 128; st++) {
    // issue next-step prefetches + this step's A-weight stream early
    const int st1 = (st < 127) ? st + 1 : 127;
    float wht_n = (kgA == 0) ? wht_g[((size_t)b * 128 + st1) * 128 + jA] : 0.f;
    float gp_n  = (kgE == 0) ? Gp_g[((size_t)b * 128 + st1) * 256 + iE] : 0.f;
    float pf_n  = (kgE == 0 && iE >= 128) ? pf[((size_t)b * 128 + st1) * 128 + (iE - 128)] : 0.f;
    float4 w0 = *(const float4*)(wr_p);
    float4 w1 = *(const float4*)(wr_p + 4);
    float4 w2 = *(const float4*)(wr_p + 8);
    float4 w3 = *(const float4*)(wr_p + 12);

    // ---- stage h (parity st&1; zeros at st=0)
    if (t < 128) {
      float hv = ld_agent(h_ex + (st & 1) * 2048 + b * 128 + t);
      h_s[HIDX(t)] = hv;
      xh_s[xIdxH] = hv;
    }
    __syncthreads();

    // ---- A: tu = tanh(h@Wr^T + wrb + wht)   [redundant; weights streamed]
    {
      const float* hp = h_s + kgA * 20;
      float4 h0 = *(const float4*)(hp), h1 = *(const float4*)(hp + 4);
      float4 h2 = *(const float4*)(hp + 8), h3 = *(const float4*)(hp + 12);
      float acc = h0.x * w0.x + h0.y * w0.y + h0.z * w0.z + h0.w * w0.w;
      acc = fmaf(h1.x, w1.x, acc); acc = fmaf(h1.y, w1.y, acc);
      acc = fmaf(h1.z, w1.z, acc); acc = fmaf(h1.w, w1.w, acc);
      acc = fmaf(h2.x, w2.x, acc); acc = fmaf(h2.y, w2.y, acc);
      acc = fmaf(h2.z, w2.z, acc); acc = fmaf(h2.w, w2.w, acc);
      acc = fmaf(h3.x, w3.x, acc); acc = fmaf(h3.y, w3.y, acc);
      acc = fmaf(h3.z, w3.z, acc); acc = fmaf(h3.w, w3.w, acc);
      acc += __shfl_xor(acc, 1);
      acc += __shfl_xor(acc, 2);
      acc += __shfl_xor(acc, 4);
      if (kgA == 0) tu_s[TUIDX(jA)] = tanh_fast(acc + wrb_r + wht_c);
    }
    __syncthreads();

    // ---- B: all 256 scores locally; ta recomputed from whs (exp-tanh).
    // jj-order rotated by hg to spread LDS banks.
    {
      const float* wq = whs_l + qB * 132 + hgB * 32;
      const float* tu_p = tu_s + hgB * 36;
      const float* we_p = wew_s + hgB * 36;
      float acc = 0.f;
#pragma unroll
      for (int jj = 0; jj < 8; jj++) {
        const int jr = (((jj + 2 * hgB) & 7) << 2);
        float4 S4 = *(const float4*)(wq + jr);
        float4 U4 = *(const float4*)(tu_p + jr);
        float4 W4 = *(const float4*)(we_p + jr);
        float ax = tanh_fast(S4.x), ay = tanh_fast(S4.y),
              az = tanh_fast(S4.z), aw = tanh_fast(S4.w);
        acc = fmaf((ax + U4.x) * frcp(fmaxf(fmaf(ax, U4.x, 1.f), 1e-6f)), W4.x, acc);
        acc = fmaf((ay + U4.y) * frcp(fmaxf(fmaf(ay, U4.y, 1.f), 1e-6f)), W4.y, acc);
        acc = fmaf((az + U4.z) * frcp(fmaxf(fmaf(az, U4.z, 1.f), 1e-6f)), W4.z, acc);
        acc = fmaf((aw + U4.w) * frcp(fmaxf(fmaf(aw, U4.w, 1.f), 1e-6f)), W4.w, acc);
      }
      acc += __shfl_xor(acc, 1);
      acc += __shfl_xor(acc, 2);
      if (hgB == 0) sc_s[SCIDX(qB)] = acc + web_r;
    }
    __syncthreads();

    // ---- softmax stats (per-wave redundant) + D: alpha
    {
      const int lane = t & 63;
      float s0 = sc_s[SCIDX(lane)];
      float s1 = sc_s[SCIDX(lane + 64)];
      float s2 = sc_s[SCIDX(lane + 128)];
      float s3 = sc_s[SCIDX(lane + 192)];
      float mx = fmaxf(fmaxf(s0, s1), fmaxf(s2, s3));
#pragma unroll
      for (int d = 1; d < 64; d <<= 1) mx = fmaxf(mx, __shfl_xor(mx, d));
      float sum = __expf(s0 - mx) + __expf(s1 - mx) +
                  __expf(s2 - mx) + __expf(s3 - mx);
#pragma unroll
      for (int d = 1; d < 64; d <<= 1) sum += __shfl_xor(sum, d);
      float inv = frcp(sum);
      const float* whs_p = whs_l + qgD * 132 + hD;
      const float* scp = sc_s + qgD;
      float acc = 0.f;
#pragma unroll 8
      for (int r = 0; r < 32; r++) {     // q = qgD + 8r
        float e = __expf(scp[(r >> 2) * 36 + ((r & 3) << 3)] - mx);
        acc = fmaf(e, whs_p[r * 1056], acc);
      }
      acc += __shfl_xor(acc, 1);
      acc += __shfl_xor(acc, 2);
      acc += __shfl_xor(acc, 4);
      if (qgD == 0) alpha_s[AIDX(hD)] = acc * inv;
    }
    __syncthreads();

    // ---- E: gate = sigmoid(Wg[:,:128]@alpha + Gp); xh = gate*[alpha;p]
    {
      const float* al_p = alpha_s + kgE * 36;
      float acc = 0.f;
#pragma unroll
      for (int rr = 0; rr < 8; rr++) {
        float4 a4 = *(const float4*)(al_p + (rr << 2));
        acc = fmaf(wE[rr * 4 + 0], a4.x, acc);
        acc = fmaf(wE[rr * 4 + 1], a4.y, acc);
        acc = fmaf(wE[rr * 4 + 2], a4.z, acc);
        acc = fmaf(wE[rr * 4 + 3], a4.w, acc);
      }
      acc += __shfl_xor(acc, 1);
      acc += __shfl_xor(acc, 2);
      if (kgE == 0) {
        float sg = sigm(gp_c + acc);
        float xv = (iE < 128) ? alpha_s[aIdxE] : pf_c;
        xh_s[xIdxE] = sg * xv;
      }
    }
    __syncthreads();

    // ---- F: gates slice = WT[64 rows]@[xh;h]   [split 8-way: 96KB/step]
    {
      const float* Wb = WTp + (size_t)(kgF * 6) * 2048 + rowF * 4;
      const float* xb = xh_s + kgF * 28;
      float acc = 0.f;
#pragma unroll
      for (int r4 = 0; r4 < 6; r4++) {
        float4 w4 = *(const float4*)(Wb + (size_t)r4 * 2048);
        float4 x4 = *(const float4*)(xb + (r4 << 2));
        acc = fmaf(w4.x, x4.x, acc);
        acc = fmaf(w4.y, x4.y, acc);
        acc = fmaf(w4.z, x4.z, acc);
        acc = fmaf(w4.w, x4.w, acc);
      }
      acc += __shfl_xor(acc, 1);
      acc += __shfl_xor(acc, 2);
      acc += __shfl_xor(acc, 4);
      acc += __shfl_xor(acc, 8);
      if (kgF == 0) gates_s[iF] = acc + bbF_r;
    }
    __syncthreads();

    // ---- cell: 16-h slice; publish h
    if (t < 16) {
      float iv = sigm(gates_s[t]);
      float fv = sigm(gates_s[16 + t]);
      float gv = tanh_fast(gates_s[32 + t]);
      float ov = sigm(gates_s[48 + t]);
      float cn = fmaf(fv, c_r, iv * gv);
      float hn = ov * tanh_fast(cn);
      c_r = cn;
      st_agent(h_ex + ((st + 1) & 1) * 2048 + b * 128 + (kblk << 4) + t, hn);
      out[((size_t)b * 128 + st) * 128 + (kblk << 4) + t] = hn;
    }
    if (st < 127) {
      __syncthreads();                       // drains vmcnt -> stores in L2
      if (t == 0)
        __hip_atomic_fetch_add(ctr_b + st, 1u, __ATOMIC_RELEASE,
                               __HIP_MEMORY_SCOPE_AGENT);
      while (__hip_atomic_load(ctr_b + st, __ATOMIC_ACQUIRE,
                               __HIP_MEMORY_SCOPE_AGENT) < 8u)
        __builtin_amdgcn_s_sleep(1);
    }
    wht_c = wht_n; gp_c = gp_n; pf_c = pf_n;
  }
}

// ----------------------------------------------------------------- launcher
extern "C" void kernel_launch(void* const* d_in, const int* in_sizes, int n_in,
                              void* d_out, int out_size, void* d_ws, size_t ws_size,
                              hipStream_t stream) {
  static const int SZ_DICT[18] = {262144, 524288, 16384, 128, 16384, 128,
                                  16384, 128, 128, 1, 65536, 256,
                                  131072, 65536, 512, 512, 2048, 4096};
  static const int ALPHA2DICT[18] = {9, 8, 11, 10, 13, 12, 7, 6, 3, 2, 5, 4,
                                     15, 14, 0, 16, 1, 17};
  const void* in[18];
  for (int i = 0; i < 18; i++) in[i] = (i < n_in) ? d_in[i] : nullptr;

  bool dict_ok = true;
  int lim = (n_in < 16) ? n_in : 16;
  for (int i = 0; i < lim; i++) if (in_sizes[i] != SZ_DICT[i]) dict_ok = false;
  if (!dict_ok) {
    bool alpha_ok = true;
    for (int s = 0; s < n_in && s < 18; s++)
      if (in_sizes[s] != SZ_DICT[ALPHA2DICT[s]]) alpha_ok = false;
    if (alpha_ok)
      for (int s = 0; s < n_in && s < 18; s++) in[ALPHA2DICT[s]] = d_in[s];
  }

  const void* p   = in[0];  const void* q   = in[1];
  const void* Wsw = in[2];  const void* Wsb = in[3];
  const void* Wtw = in[4];  const void* Wtb = in[5];
  const void* Wrw = in[6];  const void* Wrb = in[7];
  const void* Wew = in[8];  const void* Web = in[9];
  const void* Wgw = in[10]; const void* Wgb = in[11];
  const void* Wih = in[12]; const void* Whh = in[13];
  const void* bih = in[14]; const void* bhh = in[15];

  float* ws = (float*)d_ws;
  float* whs  = ws;                      // 524288
  float* pff  = whs + 524288;            // 262144
  float* wht  = pff + 262144;            // 262144
  float* Gp   = wht + 262144;            // 524288
  float* WrT2 = Gp + 524288;             // 16384
  float* WgT  = WrT2 + 16384;            // 32768
  float* WTp  = WgT + 32768;             // 196608
  float* bb   = WTp + 196608;            // 512
  float* wrb  = bb + 512;                // 128
  float* wew  = wrb + 128;               // 128
  float* web  = wew + 128;               // 4 (1 used)
  uint32_t* flag = (uint32_t*)(web + 4); // 4
  float* h_ex = (float*)(flag + 4);      // 4096 (2 parities x 16 x 128)
  uint32_t* ctrp = (uint32_t*)(h_ex + 4096); // 2048 (16 x 128)  ~7.3 MB total

  hipLaunchKernelGGL(detect_kernel, dim3(1), dim3(256), 0, stream,
                     (const uint16_t*)q, flag);
  hipLaunchKernelGGL(pack2, dim3(2012), dim3(256), 0, stream,
                     p, Wrw, Wrb, Wew, Web, Wgw, Wih, Whh, bih, bhh,
                     pff, WrT2, wrb, wew, web, WgT, WTp, bb, flag,
                     h_ex, ctrp);
  hipLaunchKernelGGL(gemm3, dim3(512), dim3(256), 0, stream,
                     q, p, Wsw, Wsb, Wtw, Wtb, Wgw, Wgb, whs, wht, Gp, flag);

  float* outf = (float*)d_out;
  const float* a0 = pff;  const float* a1 = whs;  const float* a2 = wht;
  const float* a3 = Gp;   const float* a4 = WrT2; const float* a5 = wrb;
  const float* a6 = wew;  const float* a7 = web;  const float* a8 = WgT;
  const float* a9 = WTp;  const float* a10 = bb;
  float* a11 = h_ex;      uint32_t* a12 = ctrp;   float* a13 = outf;
  void* kargs[14] = {
    (void*)&a0, (void*)&a1, (void*)&a2, (void*)&a3, (void*)&a4,
    (void*)&a5, (void*)&a6, (void*)&a7, (void*)&a8, (void*)&a9,
    (void*)&a10, (void*)&a11, (void*)&a12, (void*)&a13
  };
  hipLaunchCooperativeKernel((const void*)mlstm_seq6, dim3(128), dim3(1024),
                             kargs, 0, stream);
}

// Round 5
// 3152.444 us; speedup vs baseline: 1.9667x; 1.9667x over previous
//
#include <hip/hip_runtime.h>
#include <hip/hip_fp16.h>
#include <cstdint>

// mLstm  B=16, P=128, Q=256, D=128, H=128. fp32 in/out.
// R10 = R9 with the pack2 grid-size bug fixed (R9 post-mortem: grid covered
// 295168 of 302977 init elements -> att_ctr/gate_ctr NEVER ZEROED -> garbage
// counters defeated the handshake -> absmax 0.62. Architecture unchanged.)
// R9 design: weight-stationary split. 16 attention blocks (batch-resident:
// whs fp32 LDS; A/B/softmax/D/E + cell; WrT streamed fp16 32KB/step; wE fp16
// 16 regs) + 128 gate blocks (4 rows x 384 LSTM GEMV weights in LDS, zero
// per-step weight traffic, serve all 16 batches). One xh->gates roundtrip per
// step: att_ctr[st] (16 adds, gate leaders spin) / gate_ctr[st][8] shards
// (att lanes t<8 spin). Leader-only spins (R8's all-thread spin = 4x loss).
// Register arrays <=16 u32 (R6-R8: bigger residency spills at 64-VGPR cap).

__device__ __forceinline__ float bf2f(uint16_t u) {
  uint32_t x = ((uint32_t)u) << 16; float f; __builtin_memcpy(&f, &x, 4); return f;
}
__device__ __forceinline__ float load_in(const void* p, size_t i, int f32) {
  return f32 ? ((const float*)p)[i] : bf2f(((const uint16_t*)p)[i]);
}
__device__ __forceinline__ float frcp(float x) { return __builtin_amdgcn_rcpf(x); }
__device__ __forceinline__ float tanh_fast(float x) {
  float E = __expf(2.0f * x);
  return 1.0f - 2.0f * frcp(E + 1.0f);
}
__device__ __forceinline__ float sigm(float x) { return frcp(1.0f + __expf(-x)); }
__device__ __forceinline__ void st_agent(float* p, float v) {
  __hip_atomic_store(p, v, __ATOMIC_RELAXED, __HIP_MEMORY_SCOPE_AGENT);
}
__device__ __forceinline__ float ld_agent(const float* p) {
  return __hip_atomic_load(p, __ATOMIC_RELAXED, __HIP_MEMORY_SCOPE_AGENT);
}
__device__ __forceinline__ float2 h2f(uint32_t u) {
  __half2 h; __builtin_memcpy(&h, &u, 4); return __half22float2(h);
}
__device__ __forceinline__ uint32_t f2h(float a, float b) {
  __half2 h = __floats2half2_rn(a, b);
  uint32_t u; __builtin_memcpy(&u, &h, 4); return u;
}

// ------------------------------------------------------------- detect kernel
__global__ void detect_kernel(const uint16_t* __restrict__ q16,
                              uint32_t* __restrict__ flag) {
  __shared__ int cnt;
  if (threadIdx.x == 0) cnt = 0;
  __syncthreads();
  int bad = 0;
  for (int i = threadIdx.x; i < 4096; i += 256) {
    int e = (q16[i] >> 7) & 0xFF;
    if (e > 0x8A) bad++;
  }
  atomicAdd(&cnt, bad);
  __syncthreads();
  if (threadIdx.x == 0) *flag = (cnt > 16) ? 1u : 0u;
}

// ------------------------------------------------- convert + pack (fp16 wts)
// Total init elements: 262144+8192+128+128+1+16384+512+6144+8192+128+1024
// = 302977  ->  grid 1184 x 256 (R10 fix; R9 launched 1153 and left the
// counters un-zeroed).
__global__ void pack2(const void* __restrict__ p,
                      const void* __restrict__ Wr,  const void* __restrict__ Wrb_,
                      const void* __restrict__ Wew_, const void* __restrict__ Web_,
                      const void* __restrict__ Wg,
                      const void* __restrict__ bih, const void* __restrict__ bhh,
                      float* __restrict__ pf,
                      uint32_t* __restrict__ WrTh, float* __restrict__ wrb,
                      float* __restrict__ wew, float* __restrict__ web,
                      uint32_t* __restrict__ WgTh, float* __restrict__ bbv,
                      const uint32_t* __restrict__ flag,
                      float* __restrict__ xh_ex, float* __restrict__ gates_ex,
                      uint32_t* __restrict__ attc, uint32_t* __restrict__ gatec) {
  const int f32 = (int)*flag;
  long idx = (long)blockIdx.x * blockDim.x + threadIdx.x;
  if (idx < 262144) { pf[idx] = load_in(p, idx, f32); return; }
  idx -= 262144;
  if (idx < 8192) { int kp = idx >> 7, j = idx & 127;
    WrTh[idx] = f2h(load_in(Wr, (size_t)j * 128 + 2 * kp, f32),
                    load_in(Wr, (size_t)j * 128 + 2 * kp + 1, f32)); return; }
  idx -= 8192;
  if (idx < 128) { wrb[idx] = load_in(Wrb_, idx, f32); return; }
  idx -= 128;
  if (idx < 128) { wew[idx] = load_in(Wew_, idx, f32); return; }
  idx -= 128;
  if (idx < 1) { web[0] = load_in(Web_, 0, f32); return; }
  idx -= 1;
  if (idx < 16384) { int kp = idx >> 8, i = idx & 255;
    WgTh[idx] = f2h(load_in(Wg, (size_t)i * 256 + 2 * kp, f32),
                    load_in(Wg, (size_t)i * 256 + 2 * kp + 1, f32)); return; }
  idx -= 16384;
  if (idx < 512) { bbv[idx] = load_in(bih, idx, f32) + load_in(bhh, idx, f32); return; }
  idx -= 512;
  if (idx < 6144) { xh_ex[idx] = 0.f; return; }
  idx -= 6144;
  if (idx < 8192) { gates_ex[idx] = 0.f; return; }
  idx -= 8192;
  if (idx < 128) { attc[idx] = 0u; return; }
  idx -= 128;
  if (idx < 1024) { gatec[idx] = 0u; return; }
}

// --------------------------------------------- fused 3-way small GEMM (K=128)
__global__ __launch_bounds__(256) void gemm3(
    const void* __restrict__ q, const void* __restrict__ p,
    const void* __restrict__ Wsw, const void* __restrict__ Wsb,
    const void* __restrict__ Wtw, const void* __restrict__ Wtb,
    const void* __restrict__ Wgw, const void* __restrict__ Wgb,
    float* __restrict__ whs, float* __restrict__ wht, float* __restrict__ Gp,
    const uint32_t* __restrict__ flag) {
  __shared__ float A_l[16][128];
  __shared__ float W_l[64][129];
  const int f32 = (int)*flag;
  const int t = threadIdx.x;
  const void* A; const void* W; const void* bias; float* out;
  int lda = 128, ldw, w_off, C, r0;
  int blk = blockIdx.x;
  if (blk < 256)      { A = q; W = Wsw; bias = Wsb; out = whs; ldw = 128; w_off = 0;   C = 128; r0 = blk * 16; }
  else if (blk < 384) { A = p; W = Wtw; bias = Wtb; out = wht; ldw = 128; w_off = 0;   C = 128; r0 = (blk - 256) * 16; }
  else                { A = p; W = Wgw; bias = Wgb; out = Gp;  ldw = 256; w_off = 128; C = 256; r0 = (blk - 384) * 16; }
  for (int idx = t; idx < 16 * 128; idx += 256) {
    int rr = idx >> 7, kk = idx & 127;
    A_l[rr][kk] = load_in(A, (size_t)(r0 + rr) * lda + kk, f32);
  }
  const int c_l = t & 63, rg = t >> 6;
  for (int c0 = 0; c0 < C; c0 += 64) {
    __syncthreads();
    for (int idx = t; idx < 64 * 128; idx += 256) {
      int cc = idx >> 7, kk = idx & 127;
      W_l[cc][kk] = load_in(W, (size_t)w_off + (size_t)(c0 + cc) * ldw + kk, f32);
    }
    __syncthreads();
    float acc[4] = {0.f, 0.f, 0.f, 0.f};
    for (int k = 0; k < 128; k++) {
      float w = W_l[c_l][k];
#pragma unroll
      for (int x = 0; x < 4; x++) acc[x] = fmaf(A_l[rg * 4 + x][k], w, acc[x]);
    }
    float bv = load_in(bias, c0 + c_l, f32);
#pragma unroll
    for (int x = 0; x < 4; x++)
      out[(size_t)(r0 + rg * 4 + x) * C + c0 + c_l] = acc[x] + bv;
  }
}

// ---------------------------------------------------------- sequential kernel
// blocks 0..15: attention (batch = blockIdx); blocks 16..143: gate servers.
#define TUIDX(j) ((((j) >> 5) * 36) + ((j) & 31))
#define SCIDX(q) ((((q) >> 5) * 36) + ((q) & 31))
#define AIDX(h)  ((((h) >> 5) * 36) + ((h) & 31))
#define HIDX(k)  ((((k) >> 4) * 20) + ((k) & 15))

__global__ __launch_bounds__(1024) void mlstm_seq7(
    const float* __restrict__ pf,    // [16][128][128]
    const float* __restrict__ whs,   // [16][256][128]
    const float* __restrict__ wht_g, // [16][128][128]
    const float* __restrict__ Gp_g,  // [16][128][256]
    const uint32_t* __restrict__ WrTh, // [64][128] half2 pairs over k
    const float* __restrict__ wrb,   // [128]
    const float* __restrict__ wew,   // [128]
    const float* __restrict__ web,   // [1]
    const uint32_t* __restrict__ WgTh, // [64][256] half2 pairs over k(<128)
    const float* __restrict__ bbv,   // [512]
    const void* __restrict__ Wih,    // raw [512][256]
    const void* __restrict__ Whh,    // raw [512][128]
    const uint32_t* __restrict__ flag,
    float* __restrict__ xh_ex,       // [16][384]  ([0:256)=g*x, [256:384)=h)
    float* __restrict__ gates_ex,    // [16][512]  (bias included)
    uint32_t* __restrict__ att_ctr,  // [128]
    uint32_t* __restrict__ gate_ctr, // [128][8]
    float* __restrict__ out) {       // [16][128][128]
  const int t = threadIdx.x;
  __shared__ __align__(16) char smem[139728];

  if (blockIdx.x < 16) {
    // ================= attention block =================
    const int b = blockIdx.x;
    float* whs_l  = (float*)smem;                 // 256x132 = 135168 B
    float* u2_s   = (float*)(smem + 135168);      // 144
    float* wew_s  = (float*)(smem + 135744);      // 144
    float* sc_s   = (float*)(smem + 136320);      // 288
    float* e_s    = (float*)(smem + 137472);      // 256
    float* alpha_s= (float*)(smem + 138496);      // 144
    float* h_s    = (float*)(smem + 139072);      // 160
    float* inv_s  = (float*)(smem + 139712);      // 1

    const float* whs_b = whs + (size_t)b * 32768;
    for (int i4 = t; i4 < 8192; i4 += 1024)
      *(float4*)(whs_l + (i4 >> 5) * 132 + ((i4 & 31) << 2)) =
          *(const float4*)(whs_b + ((size_t)i4 << 2));
    if (t < 128) wew_s[TUIDX(t)] = wew[t];
    if (t < 160) h_s[t] = 0.f;

    const int jA = t >> 3, kgA = t & 7;   // A: 128 j x 8 kg (8 k-pairs)
    const int qB = t >> 2, hgB = t & 3;   // B: 256 q x 4 hg (32 h)
    const int hD = t >> 3, qgD = t & 7;   // D: 128 h x 8 qg (32 q interleaved)
    const int iE = t >> 2, kgE = t & 3;   // E: 256 i x 4 kg (16 k-pairs)

    uint32_t wEh[16];
#pragma unroll
    for (int r = 0; r < 16; r++) wEh[r] = WgTh[(size_t)(kgE * 16 + r) * 256 + iE];
    const float wrb_r = wrb[jA];
    const float web_r = web[0];
    float c_r = 0.f;
    const uint32_t* wrp = WrTh + (size_t)(kgA * 8) * 128 + jA;
    __syncthreads();

    for (int st = 0; st < 128; st++) {
      // ---- A: u2 = 2*(h@Wr^T + wrb + wht)   (weights fp16, streamed)
      {
        float acc = 0.f;
#pragma unroll
        for (int rr = 0; rr < 8; rr++) {
          float2 wf = h2f(wrp[(size_t)rr * 128]);
          float2 hv = *(const float2*)(h_s + kgA * 20 + rr * 2);
          acc = fmaf(hv.x, wf.x, fmaf(hv.y, wf.y, acc));
        }
        acc += __shfl_xor(acc, 1);
        acc += __shfl_xor(acc, 2);
        acc += __shfl_xor(acc, 4);
        if (kgA == 0)
          u2_s[TUIDX(jA)] =
              2.0f * (acc + wrb_r + wht_g[((size_t)b * 128 + st) * 128 + jA]);
      }
      __syncthreads();

      // ---- B: sc[q] = sum_h we_h * tanh(whs + u); tanh = 1-2/(exp(2whs+u2)+1)
      {
        const float* wq = whs_l + qB * 132 + hgB * 32;
        const float* up = u2_s + hgB * 36;
        const float* wp = wew_s + hgB * 36;
        float acc = 0.f;
#pragma unroll
        for (int jj = 0; jj < 8; jj++) {
          const int jr = (((jj + 2 * hgB) & 7) << 2);
          float4 S = *(const float4*)(wq + jr);
          float4 U = *(const float4*)(up + jr);
          float4 W = *(const float4*)(wp + jr);
          acc = fmaf(1.f - 2.f * frcp(__expf(fmaf(2.f, S.x, U.x)) + 1.f), W.x, acc);
          acc = fmaf(1.f - 2.f * frcp(__expf(fmaf(2.f, S.y, U.y)) + 1.f), W.y, acc);
          acc = fmaf(1.f - 2.f * frcp(__expf(fmaf(2.f, S.z, U.z)) + 1.f), W.z, acc);
          acc = fmaf(1.f - 2.f * frcp(__expf(fmaf(2.f, S.w, U.w)) + 1.f), W.w, acc);
        }
        acc += __shfl_xor(acc, 1);
        acc += __shfl_xor(acc, 2);
        if (hgB == 0) sc_s[SCIDX(qB)] = acc + web_r;
      }
      __syncthreads();

      // ---- C: softmax stats + e_s (wave 0)
      if (t < 64) {
        float s0 = sc_s[SCIDX(t)],       s1 = sc_s[SCIDX(t + 64)];
        float s2 = sc_s[SCIDX(t + 128)], s3 = sc_s[SCIDX(t + 192)];
        float mx = fmaxf(fmaxf(s0, s1), fmaxf(s2, s3));
#pragma unroll
        for (int d = 1; d < 64; d <<= 1) mx = fmaxf(mx, __shfl_xor(mx, d));
        float e0 = __expf(s0 - mx), e1 = __expf(s1 - mx),
              e2 = __expf(s2 - mx), e3 = __expf(s3 - mx);
        float sum = e0 + e1 + e2 + e3;
#pragma unroll
        for (int d = 1; d < 64; d <<= 1) sum += __shfl_xor(sum, d);
        e_s[t] = e0; e_s[t + 64] = e1; e_s[t + 128] = e2; e_s[t + 192] = e3;
        if (t == 0) inv_s[0] = frcp(sum);
      }
      __syncthreads();

      // ---- D: alpha = (sum_q e[q]*whs[q][h]) * inv
      {
        const float* whs_p = whs_l + qgD * 132 + hD;
        float acc = 0.f;
#pragma unroll 8
        for (int r = 0; r < 32; r++)
          acc = fmaf(e_s[qgD + 8 * r], whs_p[r * 1056], acc);
        acc += __shfl_xor(acc, 1);
        acc += __shfl_xor(acc, 2);
        acc += __shfl_xor(acc, 4);
        if (qgD == 0) alpha_s[AIDX(hD)] = acc * inv_s[0];
      }
      __syncthreads();

      // ---- E: gate = sigmoid(Wg[:,:128]@alpha + Gp); publish xh = gate*[alpha;p]
      {
        const float* al = alpha_s + kgE * 36;
        float acc = 0.f;
#pragma unroll
        for (int rr = 0; rr < 16; rr++) {
          float2 wf = h2f(wEh[rr]);
          float2 av = *(const float2*)(al + rr * 2);
          acc = fmaf(av.x, wf.x, fmaf(av.y, wf.y, acc));
        }
        acc += __shfl_xor(acc, 1);
        acc += __shfl_xor(acc, 2);
        if (kgE == 0) {
          float gp = Gp_g[((size_t)b * 128 + st) * 256 + iE];
          float sg = sigm(gp + acc);
          float xv = (iE < 128) ? alpha_s[AIDX(iE)]
                                : pf[((size_t)b * 128 + st) * 128 + (iE - 128)];
          st_agent(xh_ex + b * 384 + iE, sg * xv);
        }
      }
      __syncthreads();                       // drain xh stores (vmcnt before bar)
      if (t == 0)
        __hip_atomic_fetch_add(att_ctr + st, 1u, __ATOMIC_RELEASE,
                               __HIP_MEMORY_SCOPE_AGENT);
      if (t < 8) {                           // leader lanes spin on 8 shards
        while (__hip_atomic_load(gate_ctr + st * 8 + t, __ATOMIC_ACQUIRE,
                                 __HIP_MEMORY_SCOPE_AGENT) < 16u)
          __builtin_amdgcn_s_sleep(1);
      }
      __syncthreads();

      // ---- cell (gates include bias)
      if (t < 128) {
        float gi = ld_agent(gates_ex + b * 512 + t);
        float gf = ld_agent(gates_ex + b * 512 + 128 + t);
        float gg = ld_agent(gates_ex + b * 512 + 256 + t);
        float go = ld_agent(gates_ex + b * 512 + 384 + t);
        float iv = sigm(gi), fv = sigm(gf), ov = sigm(go);
        float gv = tanh_fast(gg);
        float cn = fmaf(fv, c_r, iv * gv);
        float hn = ov * tanh_fast(cn);
        c_r = cn;
        h_s[HIDX(t)] = hn;
        st_agent(xh_ex + b * 384 + 256 + t, hn);   // h-part for next step's F
        out[((size_t)b * 128 + st) * 128 + t] = hn;
      }
      __syncthreads();
    }
  } else {
    // ================= gate server block =================
    const int g = blockIdx.x - 16;            // 0..127, rows g*4..g*4+3
    float* w_l  = (float*)smem;               // [4][16][28] = 7168 B
    float* xh_l = (float*)(smem + 7168);      // [16][452]   = 28928 B
    const int f32 = (int)*flag;
    const int r = t >> 8, bb_i = (t >> 4) & 15, kq = t & 15;
    const int rowabs = g * 4 + r;

    for (int idx = t; idx < 1536; idx += 1024) {
      int rr = idx / 384, k = idx % 384;
      int row = g * 4 + rr;
      float v = (k < 256) ? load_in(Wih, (size_t)row * 256 + k, f32)
                          : load_in(Whh, (size_t)row * 128 + (k - 256), f32);
      w_l[rr * 448 + (k / 24) * 28 + (k % 24)] = v;
    }
    const float bias_r = bbv[rowabs];
    const float* wp = w_l + r * 448 + kq * 28;
    const float* xp = xh_l + bb_i * 452 + kq * 28;
    const int shard = g & 7;

    for (int st = 0; st < 128; st++) {
      if (t == 0) {
        while (__hip_atomic_load(att_ctr + st, __ATOMIC_ACQUIRE,
                                 __HIP_MEMORY_SCOPE_AGENT) < 16u)
          __builtin_amdgcn_s_sleep(1);
      }
      __syncthreads();
      for (int idx = t; idx < 6144; idx += 1024) {   // stage xh: 16 x 384
        int bbx = idx / 384, k = idx % 384;
        xh_l[bbx * 452 + (k / 24) * 28 + (k % 24)] = ld_agent(xh_ex + idx);
      }
      __syncthreads();
      float acc = 0.f;
#pragma unroll
      for (int j4 = 0; j4 < 6; j4++) {
        float4 w4 = *(const float4*)(wp + (j4 << 2));
        float4 x4 = *(const float4*)(xp + (j4 << 2));
        acc = fmaf(w4.x, x4.x, acc);
        acc = fmaf(w4.y, x4.y, acc);
        acc = fmaf(w4.z, x4.z, acc);
        acc = fmaf(w4.w, x4.w, acc);
      }
      acc += __shfl_xor(acc, 1);
      acc += __shfl_xor(acc, 2);
      acc += __shfl_xor(acc, 4);
      acc += __shfl_xor(acc, 8);
      if (kq == 0) st_agent(gates_ex + bb_i * 512 + rowabs, acc + bias_r);
      __syncthreads();                       // drain gates stores
      if (t == 0)
        __hip_atomic_fetch_add(gate_ctr + st * 8 + shard, 1u, __ATOMIC_RELEASE,
                               __HIP_MEMORY_SCOPE_AGENT);
    }
  }
}

// ----------------------------------------------------------------- launcher
extern "C" void kernel_launch(void* const* d_in, const int* in_sizes, int n_in,
                              void* d_out, int out_size, void* d_ws, size_t ws_size,
                              hipStream_t stream) {
  static const int SZ_DICT[18] = {262144, 524288, 16384, 128, 16384, 128,
                                  16384, 128, 128, 1, 65536, 256,
                                  131072, 65536, 512, 512, 2048, 4096};
  static const int ALPHA2DICT[18] = {9, 8, 11, 10, 13, 12, 7, 6, 3, 2, 5, 4,
                                     15, 14, 0, 16, 1, 17};
  const void* in[18];
  for (int i = 0; i < 18; i++) in[i] = (i < n_in) ? d_in[i] : nullptr;

  bool dict_ok = true;
  int lim = (n_in < 16) ? n_in : 16;
  for (int i = 0; i < lim; i++) if (in_sizes[i] != SZ_DICT[i]) dict_ok = false;
  if (!dict_ok) {
    bool alpha_ok = true;
    for (int s = 0; s < n_in && s < 18; s++)
      if (in_sizes[s] != SZ_DICT[ALPHA2DICT[s]]) alpha_ok = false;
    if (alpha_ok)
      for (int s = 0; s < n_in && s < 18; s++) in[ALPHA2DICT[s]] = d_in[s];
  }

  const void* p   = in[0];  const void* q   = in[1];
  const void* Wsw = in[2];  const void* Wsb = in[3];
  const void* Wtw = in[4];  const void* Wtb = in[5];
  const void* Wrw = in[6];  const void* Wrb = in[7];
  const void* Wew = in[8];  const void* Web = in[9];
  const void* Wgw = in[10]; const void* Wgb = in[11];
  const void* Wih = in[12]; const void* Whh = in[13];
  const void* bih = in[14]; const void* bhh = in[15];

  float* ws = (float*)d_ws;
  float* whs  = ws;                          // 524288
  float* pff  = whs + 524288;                // 262144
  float* wht  = pff + 262144;                // 262144
  float* Gp   = wht + 262144;                // 524288
  uint32_t* WrTh = (uint32_t*)(Gp + 524288); // 8192
  uint32_t* WgTh = WrTh + 8192;              // 16384
  float* bbv  = (float*)(WgTh + 16384);      // 512
  float* wrb  = bbv + 512;                   // 128
  float* wew  = wrb + 128;                   // 128
  float* web  = wew + 128;                   // 4 (1 used)
  uint32_t* flag = (uint32_t*)(web + 4);     // 4
  float* xh_ex = (float*)(flag + 4);         // 6144
  float* gates_ex = xh_ex + 6144;            // 8192
  uint32_t* attc = (uint32_t*)(gates_ex + 8192); // 128
  uint32_t* gatec = attc + 128;              // 1024   (~6.5 MB total)

  hipLaunchKernelGGL(detect_kernel, dim3(1), dim3(256), 0, stream,
                     (const uint16_t*)q, flag);
  // 302977 init elements -> 1184 blocks x 256 (R10 fix)
  hipLaunchKernelGGL(pack2, dim3(1184), dim3(256), 0, stream,
                     p, Wrw, Wrb, Wew, Web, Wgw, bih, bhh,
                     pff, WrTh, wrb, wew, web, WgTh, bbv, flag,
                     xh_ex, gates_ex, attc, gatec);
  hipLaunchKernelGGL(gemm3, dim3(512), dim3(256), 0, stream,
                     q, p, Wsw, Wsb, Wtw, Wtb, Wgw, Wgb, whs, wht, Gp, flag);

  float* outf = (float*)d_out;
  const float* a0 = pff;  const float* a1 = whs;  const float* a2 = wht;
  const float* a3 = Gp;
  const uint32_t* a4 = WrTh; const float* a5 = wrb; const float* a6 = wew;
  const float* a7 = web;  const uint32_t* a8 = WgTh; const float* a9 = bbv;
  const void* a10 = Wih;  const void* a11 = Whh;  const uint32_t* a12 = flag;
  float* a13 = xh_ex;     float* a14 = gates_ex;
  uint32_t* a15 = attc;   uint32_t* a16 = gatec;  float* a17 = outf;
  void* kargs[18] = {
    (void*)&a0, (void*)&a1, (void*)&a2, (void*)&a3, (void*)&a4,
    (void*)&a5, (void*)&a6, (void*)&a7, (void*)&a8, (void*)&a9,
    (void*)&a10, (void*)&a11, (void*)&a12, (void*)&a13, (void*)&a14,
    (void*)&a15, (void*)&a16, (void*)&a17
  };
  hipLaunchCooperativeKernel((const void*)mlstm_seq7, dim3(144), dim3(1024),
                             kargs, 0, stream);
}

// Round 6
// 2265.709 us; speedup vs baseline: 2.7364x; 1.3914x over previous
//
#include <hip/hip_runtime.h>
#include <hip/hip_fp16.h>
#include <cstdint>

// mLstm  B=16, P=128, Q=256, D=128, H=128. fp32 in/out.
// R11: back to the R5-proven ALL-LOCAL structure (16 blocks x 1024, zero
// cross-block traffic; R7/R8/R10 showed every per-step cross-block handshake
// costs >= the streaming it saves). Streamed bytes cut 1.22MB -> 480KB/step:
// whs staged in LDS fp32 (135KB), tA deleted (B recomputes tanh from whs via
// exp, R8/R10-proven), WTp/WgT/WrT streamed as fp16 half2 (R10-proven
// numerics). NO register-resident weight arrays (R6/R7: spills at the 64-VGPR
// allocation), NO cooperative launch. 7 intra-block barriers/step.

__device__ __forceinline__ float bf2f(uint16_t u) {
  uint32_t x = ((uint32_t)u) << 16; float f; __builtin_memcpy(&f, &x, 4); return f;
}
__device__ __forceinline__ float load_in(const void* p, size_t i, int f32) {
  return f32 ? ((const float*)p)[i] : bf2f(((const uint16_t*)p)[i]);
}
__device__ __forceinline__ float frcp(float x) { return __builtin_amdgcn_rcpf(x); }
__device__ __forceinline__ float tanh_fast(float x) {
  float E = __expf(2.0f * x);
  return 1.0f - 2.0f * frcp(E + 1.0f);
}
__device__ __forceinline__ float sigm(float x) { return frcp(1.0f + __expf(-x)); }
__device__ __forceinline__ float2 h2f(uint32_t u) {
  __half2 h; __builtin_memcpy(&h, &u, 4); return __half22float2(h);
}
__device__ __forceinline__ uint32_t f2h(float a, float b) {
  __half2 h = __floats2half2_rn(a, b);
  uint32_t u; __builtin_memcpy(&u, &h, 4); return u;
}

// ------------------------------------------------------------- detect kernel
__global__ void detect_kernel(const uint16_t* __restrict__ q16,
                              uint32_t* __restrict__ flag) {
  __shared__ int cnt;
  if (threadIdx.x == 0) cnt = 0;
  __syncthreads();
  int bad = 0;
  for (int i = threadIdx.x; i < 4096; i += 256) {
    int e = (q16[i] >> 7) & 0xFF;
    if (e > 0x8A) bad++;
  }
  atomicAdd(&cnt, bad);
  __syncthreads();
  if (threadIdx.x == 0) *flag = (cnt > 16) ? 1u : 0u;
}

// ------------------------------------------------- convert + pack (fp16 wts)
// pf[262144]=p
// WrTh[kp*128+j]  = half2(Wr[j][2kp],  Wr[j][2kp+1])   kp<64   (8192 u32)
// wrb[128]; wew[128]; web[1]
// WgTh[kp*256+i]  = half2(Wg[i][2kp],  Wg[i][2kp+1])   kp<64   (16384 u32)
// WTh4[k4*1024+i*2+c] = half2(WT[4k4+2c][i], WT[4k4+2c+1][i])  (98304 u32)
//   WT[k][i] = k<256 ? Wih[i][k] : Whh[i][k-256]
// bbv[512] = bih+bhh
// Total 262144+8192+128+128+1+16384+98304+512 = 385793 -> grid 1508 x 256.
__global__ void pack2(const void* __restrict__ p,
                      const void* __restrict__ Wr,  const void* __restrict__ Wrb_,
                      const void* __restrict__ Wew_, const void* __restrict__ Web_,
                      const void* __restrict__ Wg,
                      const void* __restrict__ Wih, const void* __restrict__ Whh,
                      const void* __restrict__ bih, const void* __restrict__ bhh,
                      float* __restrict__ pf,
                      uint32_t* __restrict__ WrTh, float* __restrict__ wrb,
                      float* __restrict__ wew, float* __restrict__ web,
                      uint32_t* __restrict__ WgTh, uint32_t* __restrict__ WTh4,
                      float* __restrict__ bbv,
                      const uint32_t* __restrict__ flag) {
  const int f32 = (int)*flag;
  long idx = (long)blockIdx.x * blockDim.x + threadIdx.x;
  if (idx < 262144) { pf[idx] = load_in(p, idx, f32); return; }
  idx -= 262144;
  if (idx < 8192) { int kp = idx >> 7, j = idx & 127;
    WrTh[idx] = f2h(load_in(Wr, (size_t)j * 128 + 2 * kp, f32),
                    load_in(Wr, (size_t)j * 128 + 2 * kp + 1, f32)); return; }
  idx -= 8192;
  if (idx < 128) { wrb[idx] = load_in(Wrb_, idx, f32); return; }
  idx -= 128;
  if (idx < 128) { wew[idx] = load_in(Wew_, idx, f32); return; }
  idx -= 128;
  if (idx < 1) { web[0] = load_in(Web_, 0, f32); return; }
  idx -= 1;
  if (idx < 16384) { int kp = idx >> 8, i = idx & 255;
    WgTh[idx] = f2h(load_in(Wg, (size_t)i * 256 + 2 * kp, f32),
                    load_in(Wg, (size_t)i * 256 + 2 * kp + 1, f32)); return; }
  idx -= 16384;
  if (idx < 98304) {
    int k4 = (int)(idx >> 10), i = (int)((idx >> 1) & 511), c = (int)(idx & 1);
    int k = 4 * k4 + 2 * c;
    float v0 = (k < 256) ? load_in(Wih, (size_t)i * 256 + k, f32)
                         : load_in(Whh, (size_t)i * 128 + (k - 256), f32);
    float v1 = (k + 1 < 256) ? load_in(Wih, (size_t)i * 256 + k + 1, f32)
                             : load_in(Whh, (size_t)i * 128 + (k + 1 - 256), f32);
    WTh4[idx] = f2h(v0, v1);
    return; }
  idx -= 98304;
  if (idx < 512) { bbv[idx] = load_in(bih, idx, f32) + load_in(bhh, idx, f32); }
}

// --------------------------------------------- fused 3-way small GEMM (K=128)
__global__ __launch_bounds__(256) void gemm3(
    const void* __restrict__ q, const void* __restrict__ p,
    const void* __restrict__ Wsw, const void* __restrict__ Wsb,
    const void* __restrict__ Wtw, const void* __restrict__ Wtb,
    const void* __restrict__ Wgw, const void* __restrict__ Wgb,
    float* __restrict__ whs, float* __restrict__ wht, float* __restrict__ Gp,
    const uint32_t* __restrict__ flag) {
  __shared__ float A_l[16][128];
  __shared__ float W_l[64][129];
  const int f32 = (int)*flag;
  const int t = threadIdx.x;
  const void* A; const void* W; const void* bias; float* out;
  int lda = 128, ldw, w_off, C, r0;
  int blk = blockIdx.x;
  if (blk < 256)      { A = q; W = Wsw; bias = Wsb; out = whs; ldw = 128; w_off = 0;   C = 128; r0 = blk * 16; }
  else if (blk < 384) { A = p; W = Wtw; bias = Wtb; out = wht; ldw = 128; w_off = 0;   C = 128; r0 = (blk - 256) * 16; }
  else                { A = p; W = Wgw; bias = Wgb; out = Gp;  ldw = 256; w_off = 128; C = 256; r0 = (blk - 384) * 16; }
  for (int idx = t; idx < 16 * 128; idx += 256) {
    int rr = idx >> 7, kk = idx & 127;
    A_l[rr][kk] = load_in(A, (size_t)(r0 + rr) * lda + kk, f32);
  }
  const int c_l = t & 63, rg = t >> 6;
  for (int c0 = 0; c0 < C; c0 += 64) {
    __syncthreads();
    for (int idx = t; idx < 64 * 128; idx += 256) {
      int cc = idx >> 7, kk = idx & 127;
      W_l[cc][kk] = load_in(W, (size_t)w_off + (size_t)(c0 + cc) * ldw + kk, f32);
    }
    __syncthreads();
    float acc[4] = {0.f, 0.f, 0.f, 0.f};
    for (int k = 0; k < 128; k++) {
      float w = W_l[c_l][k];
#pragma unroll
      for (int x = 0; x < 4; x++) acc[x] = fmaf(A_l[rg * 4 + x][k], w, acc[x]);
    }
    float bv = load_in(bias, c0 + c_l, f32);
#pragma unroll
    for (int x = 0; x < 4; x++)
      out[(size_t)(r0 + rg * 4 + x) * C + c0 + c_l] = acc[x] + bv;
  }
}

// ---------------------------------------------------------- sequential kernel
// 16 blocks x 1024 threads, one batch per block, everything block-local.
#define TUIDX(j) ((((j) >> 5) * 36) + ((j) & 31))
#define SCIDX(q) ((((q) >> 5) * 36) + ((q) & 31))
#define AIDX(h)  ((((h) >> 5) * 36) + ((h) & 31))
#define HIDX(k)  ((((k) >> 4) * 20) + ((k) & 15))

__global__ __launch_bounds__(1024) void mlstm_seq8(
    const float* __restrict__ pf,      // [16][128][128]
    const float* __restrict__ whs,     // [16][256][128]
    const float* __restrict__ wht_g,   // [16][128][128]
    const float* __restrict__ Gp_g,    // [16][128][256]
    const uint32_t* __restrict__ WrTh, // [64][128] half2 over k
    const float* __restrict__ wrb,     // [128]
    const float* __restrict__ wew,     // [128]
    const float* __restrict__ web,     // [1]
    const uint32_t* __restrict__ WgTh, // [64][256] half2 over k(<128)
    const uint32_t* __restrict__ WTh4, // [96][512][2] half2 pairs over k
    const float* __restrict__ bbv,     // [512]
    float* __restrict__ out) {         // [16][128][128]
  const int b = blockIdx.x, t = threadIdx.x;

  __shared__ __align__(16) float whs_l[256 * 132];   // 135168 B, padded rows
  __shared__ __align__(16) float u2_s[144];
  __shared__ __align__(16) float wew_s[144];
  __shared__ __align__(16) float sc_s[288];
  __shared__ __align__(16) float e_s[256];
  __shared__ __align__(16) float alpha_s[144];
  __shared__ __align__(16) float xh_s[384];
  __shared__ __align__(16) float h_s[160];
  __shared__ __align__(16) float gates_s[512];
  __shared__ float inv_s;

  const float* whs_b = whs + (size_t)b * 32768;

  // thread mappings (reduction groups = consecutive lanes -> shfl)
  const int jA = t >> 3, kgA = t & 7;   // A: 128 j x 8 kg (8 k-pairs)
  const int qB = t >> 2, hgB = t & 3;   // B: 256 q x 4 hg (32 h)
  const int hD = t >> 3, qgD = t & 7;   // D: 128 h x 8 qg (32 q interleaved)
  const int iE = t >> 2, kgE = t & 3;   // E: 256 i x 4 kg (16 k-pairs)
  const int iF = t >> 1, kgF = t & 1;   // F: 512 rows x 2 kg (192 k = 48 k4)

  // ---- LDS init: whs into padded rows (float4), small buffers
  for (int i4 = t; i4 < 8192; i4 += 1024)
    *(float4*)(whs_l + (i4 >> 5) * 132 + ((i4 & 31) << 2)) =
        *(const float4*)(whs_b + ((size_t)i4 << 2));
  if (t < 128) wew_s[TUIDX(t)] = wew[t];
  if (t < 160) h_s[t] = 0.f;
  if (t < 128) xh_s[256 + t] = 0.f;

  const float wrb_r = wrb[jA];
  const float web_r = web[0];
  const float bbF_r = bbv[iF];
  float c_r = 0.f;                       // t<128 owners

  const uint32_t* wrp = WrTh + (size_t)(kgA * 8) * 128 + jA;
  const uint32_t* wgp = WgTh + (size_t)(kgE * 16) * 256 + iE;
  const uint2*    wtp = (const uint2*)WTh4 + (size_t)(kgF * 48) * 512 + iF;

  // per-step prefetch registers (rotate)
  float wht_c = (kgA == 0) ? wht_g[((size_t)b * 128 + 0) * 128 + jA] : 0.f;
  float gp_c  = (kgE == 0) ? Gp_g[((size_t)b * 128 + 0) * 256 + iE] : 0.f;
  float pf_c  = (kgE == 0 && iE >= 128) ? pf[((size_t)b * 128 + 0) * 128 + (iE - 128)] : 0.f;

  __syncthreads();

  for (int st = 0; st < 128; st++) {
    const int st1 = (st < 127) ? st + 1 : 127;
    float wht_n = (kgA == 0) ? wht_g[((size_t)b * 128 + st1) * 128 + jA] : 0.f;
    float gp_n  = (kgE == 0) ? Gp_g[((size_t)b * 128 + st1) * 256 + iE] : 0.f;
    float pf_n  = (kgE == 0 && iE >= 128) ? pf[((size_t)b * 128 + st1) * 128 + (iE - 128)] : 0.f;

    // ---- A: u2 = 2*(h@Wr^T + wrb + wht)   (fp16 weights streamed, 32KB)
    {
      float acc = 0.f;
#pragma unroll
      for (int rr = 0; rr < 8; rr++) {
        float2 wf = h2f(wrp[(size_t)rr * 128]);
        float2 hv = *(const float2*)(h_s + kgA * 20 + rr * 2);
        acc = fmaf(hv.x, wf.x, fmaf(hv.y, wf.y, acc));
      }
      acc += __shfl_xor(acc, 1);
      acc += __shfl_xor(acc, 2);
      acc += __shfl_xor(acc, 4);
      if (kgA == 0) u2_s[TUIDX(jA)] = 2.0f * (acc + wrb_r + wht_c);
    }
    __syncthreads();

    // ---- B: sc[q] = sum_h wew_h * tanh(whs+u), tanh = 1-2/(exp(2S+u2)+1)
    {
      const float* wq = whs_l + qB * 132 + hgB * 32;
      const float* up = u2_s + hgB * 36;
      const float* wp = wew_s + hgB * 36;
      float acc = 0.f;
#pragma unroll
      for (int jj = 0; jj < 8; jj++) {
        const int jr = (((jj + 2 * hgB) & 7) << 2);
        float4 S = *(const float4*)(wq + jr);
        float4 U = *(const float4*)(up + jr);
        float4 W = *(const float4*)(wp + jr);
        acc = fmaf(1.f - 2.f * frcp(__expf(fmaf(2.f, S.x, U.x)) + 1.f), W.x, acc);
        acc = fmaf(1.f - 2.f * frcp(__expf(fmaf(2.f, S.y, U.y)) + 1.f), W.y, acc);
        acc = fmaf(1.f - 2.f * frcp(__expf(fmaf(2.f, S.z, U.z)) + 1.f), W.z, acc);
        acc = fmaf(1.f - 2.f * frcp(__expf(fmaf(2.f, S.w, U.w)) + 1.f), W.w, acc);
      }
      acc += __shfl_xor(acc, 1);
      acc += __shfl_xor(acc, 2);
      if (hgB == 0) sc_s[SCIDX(qB)] = acc + web_r;
    }
    __syncthreads();

    // ---- C: softmax stats + e_s (wave 0)
    if (t < 64) {
      float s0 = sc_s[SCIDX(t)],       s1 = sc_s[SCIDX(t + 64)];
      float s2 = sc_s[SCIDX(t + 128)], s3 = sc_s[SCIDX(t + 192)];
      float mx = fmaxf(fmaxf(s0, s1), fmaxf(s2, s3));
#pragma unroll
      for (int d = 1; d < 64; d <<= 1) mx = fmaxf(mx, __shfl_xor(mx, d));
      float e0 = __expf(s0 - mx), e1 = __expf(s1 - mx),
            e2 = __expf(s2 - mx), e3 = __expf(s3 - mx);
      float sum = e0 + e1 + e2 + e3;
#pragma unroll
      for (int d = 1; d < 64; d <<= 1) sum += __shfl_xor(sum, d);
      e_s[t] = e0; e_s[t + 64] = e1; e_s[t + 128] = e2; e_s[t + 192] = e3;
      if (t == 0) inv_s = frcp(sum);
    }
    __syncthreads();

    // ---- D: alpha = (sum_q e[q]*whs[q][h]) * inv   (whs in LDS)
    {
      const float* whs_p = whs_l + qgD * 132 + hD;
      float acc = 0.f;
#pragma unroll 8
      for (int r = 0; r < 32; r++)        // q = qgD + 8r
        acc = fmaf(e_s[qgD + 8 * r], whs_p[r * 1056], acc);
      acc += __shfl_xor(acc, 1);
      acc += __shfl_xor(acc, 2);
      acc += __shfl_xor(acc, 4);
      if (qgD == 0) alpha_s[AIDX(hD)] = acc * inv_s;
    }
    __syncthreads();

    // ---- E: gate = sigmoid(Wg[:,:128]@alpha + Gp); xh = gate*[alpha;p]
    //      (fp16 weights streamed, 64KB)
    {
      const float* al = alpha_s + kgE * 36;
      float acc = 0.f;
#pragma unroll
      for (int rr = 0; rr < 16; rr++) {
        float2 wf = h2f(wgp[(size_t)rr * 256]);
        float2 av = *(const float2*)(al + rr * 2);
        acc = fmaf(av.x, wf.x, fmaf(av.y, wf.y, acc));
      }
      acc += __shfl_xor(acc, 1);
      acc += __shfl_xor(acc, 2);
      if (kgE == 0) {
        float sg = sigm(gp_c + acc);
        float xv = (iE < 128) ? alpha_s[AIDX(iE)] : pf_c;
        xh_s[iE] = sg * xv;
      }
    }
    __syncthreads();

    // ---- F: gates = WT[512x384]@[xh;h]   (fp16 weights streamed, 384KB)
    {
      const float* xb = xh_s + kgF * 192;
      float acc = 0.f;
#pragma unroll 8
      for (int k4 = 0; k4 < 48; k4++) {
        uint2 w = wtp[(size_t)k4 * 512];
        float4 x = *(const float4*)(xb + (k4 << 2));
        float2 w0 = h2f(w.x), w1 = h2f(w.y);
        acc = fmaf(x.x, w0.x, fmaf(x.y, w0.y,
              fmaf(x.z, w1.x, fmaf(x.w, w1.y, acc))));
      }
      acc += __shfl_xor(acc, 1);
      if (kgF == 0) gates_s[iF] = acc + bbF_r;
    }
    __syncthreads();

    // ---- cell (all local): c in regs, h to LDS, out to global
    if (t < 128) {
      float iv = sigm(gates_s[t]);
      float fv = sigm(gates_s[128 + t]);
      float gv = tanh_fast(gates_s[256 + t]);
      float ov = sigm(gates_s[384 + t]);
      float cn = fmaf(fv, c_r, iv * gv);
      float hn = ov * tanh_fast(cn);
      c_r = cn;
      h_s[HIDX(t)] = hn;
      xh_s[256 + t] = hn;
      out[((size_t)b * 128 + st) * 128 + t] = hn;
    }
    __syncthreads();

    wht_c = wht_n; gp_c = gp_n; pf_c = pf_n;
  }
}

// ----------------------------------------------------------------- launcher
extern "C" void kernel_launch(void* const* d_in, const int* in_sizes, int n_in,
                              void* d_out, int out_size, void* d_ws, size_t ws_size,
                              hipStream_t stream) {
  static const int SZ_DICT[18] = {262144, 524288, 16384, 128, 16384, 128,
                                  16384, 128, 128, 1, 65536, 256,
                                  131072, 65536, 512, 512, 2048, 4096};
  static const int ALPHA2DICT[18] = {9, 8, 11, 10, 13, 12, 7, 6, 3, 2, 5, 4,
                                     15, 14, 0, 16, 1, 17};
  const void* in[18];
  for (int i = 0; i < 18; i++) in[i] = (i < n_in) ? d_in[i] : nullptr;

  bool dict_ok = true;
  int lim = (n_in < 16) ? n_in : 16;
  for (int i = 0; i < lim; i++) if (in_sizes[i] != SZ_DICT[i]) dict_ok = false;
  if (!dict_ok) {
    bool alpha_ok = true;
    for (int s = 0; s < n_in && s < 18; s++)
      if (in_sizes[s] != SZ_DICT[ALPHA2DICT[s]]) alpha_ok = false;
    if (alpha_ok)
      for (int s = 0; s < n_in && s < 18; s++) in[ALPHA2DICT[s]] = d_in[s];
  }

  const void* p   = in[0];  const void* q   = in[1];
  const void* Wsw = in[2];  const void* Wsb = in[3];
  const void* Wtw = in[4];  const void* Wtb = in[5];
  const void* Wrw = in[6];  const void* Wrb = in[7];
  const void* Wew = in[8];  const void* Web = in[9];
  const void* Wgw = in[10]; const void* Wgb = in[11];
  const void* Wih = in[12]; const void* Whh = in[13];
  const void* bih = in[14]; const void* bhh = in[15];

  float* ws = (float*)d_ws;
  float* whs  = ws;                          // 524288
  float* pff  = whs + 524288;                // 262144
  float* wht  = pff + 262144;                // 262144
  float* Gp   = wht + 262144;                // 524288
  uint32_t* WrTh = (uint32_t*)(Gp + 524288); // 8192
  uint32_t* WgTh = WrTh + 8192;              // 16384
  uint32_t* WTh4 = WgTh + 16384;             // 98304
  float* bbv  = (float*)(WTh4 + 98304);      // 512
  float* wrb  = bbv + 512;                   // 128
  float* wew  = wrb + 128;                   // 128
  float* web  = wew + 128;                   // 4 (1 used)
  uint32_t* flag = (uint32_t*)(web + 4);     // 4       (~7.0 MB total)

  hipLaunchKernelGGL(detect_kernel, dim3(1), dim3(256), 0, stream,
                     (const uint16_t*)q, flag);
  // 385793 init elements -> 1508 blocks x 256
  hipLaunchKernelGGL(pack2, dim3(1508), dim3(256), 0, stream,
                     p, Wrw, Wrb, Wew, Web, Wgw, Wih, Whh, bih, bhh,
                     pff, WrTh, wrb, wew, web, WgTh, WTh4, bbv, flag);
  hipLaunchKernelGGL(gemm3, dim3(512), dim3(256), 0, stream,
                     q, p, Wsw, Wsb, Wtw, Wtb, Wgw, Wgb, whs, wht, Gp, flag);
  hipLaunchKernelGGL(mlstm_seq8, dim3(16), dim3(1024), 0, stream,
                     pff, whs, wht, Gp, WrTh, wrb, wew, web, WgTh, WTh4, bbv,
                     (float*)d_out);
}

// Round 7
// 1419.538 us; speedup vs baseline: 4.3675x; 1.5961x over previous
//
#include <hip/hip_runtime.h>
#include <hip/hip_fp16.h>
#include <cstdint>

// mLstm  B=16, P=128, Q=256, D=128, H=128. fp32 in/out.
// R12: R5-proven all-local structure (16 blocks x 1024) + the two R11 defects
// fixed: (1) ALL streamed weights packed in per-thread LOAD-LINEAR order
// (W[i*1024+t] = i-th uint4 of thread t's k-slice) -> every wave-load is 1KB
// fully coalesced while keeping shfl-reduce lane mappings; (2) B uses the
// R5-proven tanh addition identity with PRECOMPUTED fp16 tA (tapack kernel),
// no exps in the hot loop. whs fp32 stays in LDS for D (conflict-clean).
// Streams/step: A 32KB + B(tA) 64KB + E 64KB + F 384KB, all 16B loads.
// 7 barriers/step. No cross-block sync (R7/R8/R10), no reg-resident weight
// arrays (R6/R7 spill at the 64-VGPR allocation).

__device__ __forceinline__ float bf2f(uint16_t u) {
  uint32_t x = ((uint32_t)u) << 16; float f; __builtin_memcpy(&f, &x, 4); return f;
}
__device__ __forceinline__ float load_in(const void* p, size_t i, int f32) {
  return f32 ? ((const float*)p)[i] : bf2f(((const uint16_t*)p)[i]);
}
__device__ __forceinline__ float frcp(float x) { return __builtin_amdgcn_rcpf(x); }
__device__ __forceinline__ float tanh_fast(float x) {
  float E = __expf(2.0f * x);
  return 1.0f - 2.0f * frcp(E + 1.0f);
}
__device__ __forceinline__ float sigm(float x) { return frcp(1.0f + __expf(-x)); }
__device__ __forceinline__ float2 h2f(uint32_t u) {
  __half2 h; __builtin_memcpy(&h, &u, 4); return __half22float2(h);
}
__device__ __forceinline__ uint32_t f2h(float a, float b) {
  __half2 h = __floats2half2_rn(a, b);
  uint32_t u; __builtin_memcpy(&u, &h, 4); return u;
}

// ------------------------------------------------------------- detect kernel
__global__ void detect_kernel(const uint16_t* __restrict__ q16,
                              uint32_t* __restrict__ flag) {
  __shared__ int cnt;
  if (threadIdx.x == 0) cnt = 0;
  __syncthreads();
  int bad = 0;
  for (int i = threadIdx.x; i < 4096; i += 256) {
    int e = (q16[i] >> 7) & 0xFF;
    if (e > 0x8A) bad++;
  }
  atomicAdd(&cnt, bad);
  __syncthreads();
  if (threadIdx.x == 0) *flag = (cnt > 16) ? 1u : 0u;
}

// ------------------------------------------------- convert + pack
// Load-linear fp16 packs (u32 = one half2 pair; chunk c=i*1024+t is thread t's
// i-th uint4, u32 w in 0..3):
//  WrP [8192 u32]: jA=t>>3, kgA=t&7, k=kgA*16+i*8+w*2, pair(Wr[jA][k..k+1]), i<2
//  WgP [16384   ]: iE=t>>2, kgE=t&3, k=kgE*32+i*8+w*2, pair(Wg[iE][k..k+1]), i<4
//  WTP [98304   ]: iF=t>>1, kgF=t&1, k=kgF*192+i*8+w*2, i<24
//                  WT[k]= k<256 ? Wih[iF][k] : Whh[iF][k-256]
// bbv[512]=bih+bhh; pf; wrb; wew; web.
// Total 262144+8192+128+128+1+16384+98304+512 = 385793 -> grid 1508 x 256.
__global__ void pack2(const void* __restrict__ p,
                      const void* __restrict__ Wr,  const void* __restrict__ Wrb_,
                      const void* __restrict__ Wew_, const void* __restrict__ Web_,
                      const void* __restrict__ Wg,
                      const void* __restrict__ Wih, const void* __restrict__ Whh,
                      const void* __restrict__ bih, const void* __restrict__ bhh,
                      float* __restrict__ pf,
                      uint32_t* __restrict__ WrP, float* __restrict__ wrb,
                      float* __restrict__ wew, float* __restrict__ web,
                      uint32_t* __restrict__ WgP, uint32_t* __restrict__ WTP,
                      float* __restrict__ bbv,
                      const uint32_t* __restrict__ flag) {
  const int f32 = (int)*flag;
  long idx = (long)blockIdx.x * blockDim.x + threadIdx.x;
  if (idx < 262144) { pf[idx] = load_in(p, idx, f32); return; }
  idx -= 262144;
  if (idx < 8192) {
    int c = (int)(idx >> 2), w = (int)(idx & 3);
    int i = c >> 10, t = c & 1023;
    int jA = t >> 3, kgA = t & 7;
    int k = kgA * 16 + i * 8 + w * 2;
    WrP[idx] = f2h(load_in(Wr, (size_t)jA * 128 + k, f32),
                   load_in(Wr, (size_t)jA * 128 + k + 1, f32));
    return; }
  idx -= 8192;
  if (idx < 128) { wrb[idx] = load_in(Wrb_, idx, f32); return; }
  idx -= 128;
  if (idx < 128) { wew[idx] = load_in(Wew_, idx, f32); return; }
  idx -= 128;
  if (idx < 1) { web[0] = load_in(Web_, 0, f32); return; }
  idx -= 1;
  if (idx < 16384) {
    int c = (int)(idx >> 2), w = (int)(idx & 3);
    int i = c >> 10, t = c & 1023;
    int iE = t >> 2, kgE = t & 3;
    int k = kgE * 32 + i * 8 + w * 2;
    WgP[idx] = f2h(load_in(Wg, (size_t)iE * 256 + k, f32),
                   load_in(Wg, (size_t)iE * 256 + k + 1, f32));
    return; }
  idx -= 16384;
  if (idx < 98304) {
    int c = (int)(idx >> 2), w = (int)(idx & 3);
    int i = c >> 10, t = c & 1023;
    int iF = t >> 1, kgF = t & 1;
    int k = kgF * 192 + i * 8 + w * 2;
    float v0 = (k < 256) ? load_in(Wih, (size_t)iF * 256 + k, f32)
                         : load_in(Whh, (size_t)iF * 128 + (k - 256), f32);
    float v1 = (k + 1 < 256) ? load_in(Wih, (size_t)iF * 256 + k + 1, f32)
                             : load_in(Whh, (size_t)iF * 128 + (k + 1 - 256), f32);
    WTP[idx] = f2h(v0, v1);
    return; }
  idx -= 98304;
  if (idx < 512) { bbv[idx] = load_in(bih, idx, f32) + load_in(bhh, idx, f32); }
}

// --------------------------------------------- fused 3-way small GEMM (K=128)
__global__ __launch_bounds__(256) void gemm3(
    const void* __restrict__ q, const void* __restrict__ p,
    const void* __restrict__ Wsw, const void* __restrict__ Wsb,
    const void* __restrict__ Wtw, const void* __restrict__ Wtb,
    const void* __restrict__ Wgw, const void* __restrict__ Wgb,
    float* __restrict__ whs, float* __restrict__ wht, float* __restrict__ Gp,
    const uint32_t* __restrict__ flag) {
  __shared__ float A_l[16][128];
  __shared__ float W_l[64][129];
  const int f32 = (int)*flag;
  const int t = threadIdx.x;
  const void* A; const void* W; const void* bias; float* out;
  int lda = 128, ldw, w_off, C, r0;
  int blk = blockIdx.x;
  if (blk < 256)      { A = q; W = Wsw; bias = Wsb; out = whs; ldw = 128; w_off = 0;   C = 128; r0 = blk * 16; }
  else if (blk < 384) { A = p; W = Wtw; bias = Wtb; out = wht; ldw = 128; w_off = 0;   C = 128; r0 = (blk - 256) * 16; }
  else                { A = p; W = Wgw; bias = Wgb; out = Gp;  ldw = 256; w_off = 128; C = 256; r0 = (blk - 384) * 16; }
  for (int idx = t; idx < 16 * 128; idx += 256) {
    int rr = idx >> 7, kk = idx & 127;
    A_l[rr][kk] = load_in(A, (size_t)(r0 + rr) * lda + kk, f32);
  }
  const int c_l = t & 63, rg = t >> 6;
  for (int c0 = 0; c0 < C; c0 += 64) {
    __syncthreads();
    for (int idx = t; idx < 64 * 128; idx += 256) {
      int cc = idx >> 7, kk = idx & 127;
      W_l[cc][kk] = load_in(W, (size_t)w_off + (size_t)(c0 + cc) * ldw + kk, f32);
    }
    __syncthreads();
    float acc[4] = {0.f, 0.f, 0.f, 0.f};
    for (int k = 0; k < 128; k++) {
      float w = W_l[c_l][k];
#pragma unroll
      for (int x = 0; x < 4; x++) acc[x] = fmaf(A_l[rg * 4 + x][k], w, acc[x]);
    }
    float bv = load_in(bias, c0 + c_l, f32);
#pragma unroll
    for (int x = 0; x < 4; x++)
      out[(size_t)(r0 + rg * 4 + x) * C + c0 + c_l] = acc[x] + bv;
  }
}

// --------------------------- tA = tanh(whs) as fp16, per-thread load-linear
// TAp u32 index o: b=o>>14; r=o&16383; c=r>>2; w=r&3; i=c>>10; t=c&1023;
// qB=t>>2; hgB=t&3; h=hgB*32+i*8+w*2; value = pair(tanh(whs[b][qB][h..h+1])).
// 262144 u32 -> 1024 blocks x 256.
__global__ void tapack(const float* __restrict__ whs, uint32_t* __restrict__ TAp) {
  int o = blockIdx.x * 256 + threadIdx.x;
  int b = o >> 14, r = o & 16383;
  int c = r >> 2, w = r & 3;
  int i = c >> 10, t = c & 1023;
  int qB = t >> 2, hgB = t & 3;
  int h = hgB * 32 + i * 8 + w * 2;
  const float* base = whs + ((size_t)b * 256 + qB) * 128 + h;
  TAp[o] = f2h(tanhf(base[0]), tanhf(base[1]));
}

// ---------------------------------------------------------- sequential kernel
#define TUIDX(j) ((((j) >> 5) * 36) + ((j) & 31))
#define SCIDX(q) ((((q) >> 5) * 36) + ((q) & 31))
#define AIDX(h)  ((((h) >> 5) * 36) + ((h) & 31))
#define HIDX(k)  ((((k) >> 4) * 20) + ((k) & 15))

__global__ __launch_bounds__(1024) void mlstm_seq9(
    const float* __restrict__ pf,      // [16][128][128]
    const float* __restrict__ whs,     // [16][256][128]
    const float* __restrict__ wht_g,   // [16][128][128]
    const float* __restrict__ Gp_g,    // [16][128][256]
    const uint32_t* __restrict__ WrP,  // 8192 u32 load-linear
    const float* __restrict__ wrb,     // [128]
    const float* __restrict__ wew,     // [128]
    const float* __restrict__ web,     // [1]
    const uint32_t* __restrict__ WgP,  // 16384 u32 load-linear
    const uint32_t* __restrict__ WTP,  // 98304 u32 load-linear
    const uint32_t* __restrict__ TAp,  // [16] x 16384 u32 load-linear
    const float* __restrict__ bbv,     // [512]
    float* __restrict__ out) {         // [16][128][128]
  const int b = blockIdx.x, t = threadIdx.x;

  __shared__ __align__(16) float whs_l[256 * 132];   // 135168 B padded rows
  __shared__ __align__(16) float tu_s[144];
  __shared__ __align__(16) float wew_s[144];
  __shared__ __align__(16) float sc_s[288];
  __shared__ __align__(16) float e_s[256];
  __shared__ __align__(16) float alpha_s[144];
  __shared__ __align__(16) float xh_s[384];
  __shared__ __align__(16) float h_s[160];
  __shared__ __align__(16) float gates_s[512];
  __shared__ float inv_s;

  const float* whs_b = whs + (size_t)b * 32768;

  const int jA = t >> 3, kgA = t & 7;   // A: 128 j x 8 kg (16 k)
  const int qB = t >> 2, hgB = t & 3;   // B: 256 q x 4 hg (32 h)
  const int hD = t >> 3, qgD = t & 7;   // D: 128 h x 8 qg (32 q interleaved)
  const int iE = t >> 2, kgE = t & 3;   // E: 256 i x 4 kg (32 k)
  const int iF = t >> 1, kgF = t & 1;   // F: 512 rows x 2 kg (192 k)

  // ---- LDS init: whs fp32 padded rows (for D); small buffers
  for (int i4 = t; i4 < 8192; i4 += 1024)
    *(float4*)(whs_l + (i4 >> 5) * 132 + ((i4 & 31) << 2)) =
        *(const float4*)(whs_b + ((size_t)i4 << 2));
  if (t < 128) wew_s[TUIDX(t)] = wew[t];
  if (t < 160) h_s[t] = 0.f;
  if (t < 128) xh_s[256 + t] = 0.f;

  const float wrb_r = wrb[jA];
  const float web_r = web[0];
  const float bbF_r = bbv[iF];
  float c_r = 0.f;                       // t<128 owners

  const uint4* wrp4 = (const uint4*)WrP;                    // 2048 uint4
  const uint4* wgp4 = (const uint4*)WgP;                    // 4096 uint4
  const uint4* wtp4 = (const uint4*)WTP;                    // 24576 uint4
  const uint4* tap4 = (const uint4*)TAp + (size_t)b * 4096; // 4096 uint4

  // per-step prefetch registers (rotate)
  float wht_c = (kgA == 0) ? wht_g[((size_t)b * 128 + 0) * 128 + jA] : 0.f;
  float gp_c  = (kgE == 0) ? Gp_g[((size_t)b * 128 + 0) * 256 + iE] : 0.f;
  float pf_c  = (kgE == 0 && iE >= 128) ? pf[((size_t)b * 128 + 0) * 128 + (iE - 128)] : 0.f;

  __syncthreads();

  for (int st = 0; st < 128; st++) {
    const int st1 = (st < 127) ? st + 1 : 127;
    float wht_n = (kgA == 0) ? wht_g[((size_t)b * 128 + st1) * 128 + jA] : 0.f;
    float gp_n  = (kgE == 0) ? Gp_g[((size_t)b * 128 + st1) * 256 + iE] : 0.f;
    float pf_n  = (kgE == 0 && iE >= 128) ? pf[((size_t)b * 128 + st1) * 128 + (iE - 128)] : 0.f;

    // ---- A: tu = tanh(h@Wr^T + wrb + wht)   [2 coalesced uint4 loads]
    {
      float acc = 0.f;
#pragma unroll
      for (int i = 0; i < 2; i++) {
        uint4 wv = wrp4[i * 1024 + t];
        const float* hp = h_s + kgA * 20 + i * 8;
        float4 hA = *(const float4*)(hp);
        float4 hB = *(const float4*)(hp + 4);
        float2 w0 = h2f(wv.x), w1 = h2f(wv.y), w2 = h2f(wv.z), w3 = h2f(wv.w);
        acc = fmaf(hA.x, w0.x, acc); acc = fmaf(hA.y, w0.y, acc);
        acc = fmaf(hA.z, w1.x, acc); acc = fmaf(hA.w, w1.y, acc);
        acc = fmaf(hB.x, w2.x, acc); acc = fmaf(hB.y, w2.y, acc);
        acc = fmaf(hB.z, w3.x, acc); acc = fmaf(hB.w, w3.y, acc);
      }
      acc += __shfl_xor(acc, 1);
      acc += __shfl_xor(acc, 2);
      acc += __shfl_xor(acc, 4);
      if (kgA == 0) tu_s[TUIDX(jA)] = tanh_fast(acc + wrb_r + wht_c);
    }
    __syncthreads();

    // ---- B: sc[q] = sum_h we_h * (ta+tu)/(1+ta*tu)  [4 coalesced uint4]
    {
      float acc = 0.f;
#pragma unroll
      for (int i = 0; i < 4; i++) {
        uint4 av = tap4[i * 1024 + t];
        const float* up = tu_s + hgB * 36 + i * 8;
        const float* wp = wew_s + hgB * 36 + i * 8;
        float4 uA = *(const float4*)(up);
        float4 uB = *(const float4*)(up + 4);
        float4 wA = *(const float4*)(wp);
        float4 wB = *(const float4*)(wp + 4);
        float2 a0 = h2f(av.x), a1 = h2f(av.y), a2 = h2f(av.z), a3 = h2f(av.w);
        acc = fmaf((a0.x + uA.x) * frcp(fmaxf(fmaf(a0.x, uA.x, 1.f), 1e-6f)), wA.x, acc);
        acc = fmaf((a0.y + uA.y) * frcp(fmaxf(fmaf(a0.y, uA.y, 1.f), 1e-6f)), wA.y, acc);
        acc = fmaf((a1.x + uA.z) * frcp(fmaxf(fmaf(a1.x, uA.z, 1.f), 1e-6f)), wA.z, acc);
        acc = fmaf((a1.y + uA.w) * frcp(fmaxf(fmaf(a1.y, uA.w, 1.f), 1e-6f)), wA.w, acc);
        acc = fmaf((a2.x + uB.x) * frcp(fmaxf(fmaf(a2.x, uB.x, 1.f), 1e-6f)), wB.x, acc);
        acc = fmaf((a2.y + uB.y) * frcp(fmaxf(fmaf(a2.y, uB.y, 1.f), 1e-6f)), wB.y, acc);
        acc = fmaf((a3.x + uB.z) * frcp(fmaxf(fmaf(a3.x, uB.z, 1.f), 1e-6f)), wB.z, acc);
        acc = fmaf((a3.y + uB.w) * frcp(fmaxf(fmaf(a3.y, uB.w, 1.f), 1e-6f)), wB.w, acc);
      }
      acc += __shfl_xor(acc, 1);
      acc += __shfl_xor(acc, 2);
      if (hgB == 0) sc_s[SCIDX(qB)] = acc + web_r;
    }
    __syncthreads();

    // ---- C: softmax stats + e_s (wave 0)
    if (t < 64) {
      float s0 = sc_s[SCIDX(t)],       s1 = sc_s[SCIDX(t + 64)];
      float s2 = sc_s[SCIDX(t + 128)], s3 = sc_s[SCIDX(t + 192)];
      float mx = fmaxf(fmaxf(s0, s1), fmaxf(s2, s3));
#pragma unroll
      for (int d = 1; d < 64; d <<= 1) mx = fmaxf(mx, __shfl_xor(mx, d));
      float e0 = __expf(s0 - mx), e1 = __expf(s1 - mx),
            e2 = __expf(s2 - mx), e3 = __expf(s3 - mx);
      float sum = e0 + e1 + e2 + e3;
#pragma unroll
      for (int d = 1; d < 64; d <<= 1) sum += __shfl_xor(sum, d);
      e_s[t] = e0; e_s[t + 64] = e1; e_s[t + 128] = e2; e_s[t + 192] = e3;
      if (t == 0) inv_s = frcp(sum);
    }
    __syncthreads();

    // ---- D: alpha = (sum_q e[q]*whs[q][h]) * inv   (whs fp32 in LDS)
    {
      const float* whs_p = whs_l + qgD * 132 + hD;
      float acc = 0.f;
#pragma unroll 8
      for (int r = 0; r < 32; r++)        // q = qgD + 8r
        acc = fmaf(e_s[qgD + 8 * r], whs_p[r * 1056], acc);
      acc += __shfl_xor(acc, 1);
      acc += __shfl_xor(acc, 2);
      acc += __shfl_xor(acc, 4);
      if (qgD == 0) alpha_s[AIDX(hD)] = acc * inv_s;
    }
    __syncthreads();

    // ---- E: gate = sigmoid(Wg[:,:128]@alpha + Gp); xh = gate*[alpha;p]
    {
      float acc = 0.f;
#pragma unroll
      for (int i = 0; i < 4; i++) {
        uint4 wv = wgp4[i * 1024 + t];
        const float* ap = alpha_s + kgE * 36 + i * 8;
        float4 aA = *(const float4*)(ap);
        float4 aB = *(const float4*)(ap + 4);
        float2 w0 = h2f(wv.x), w1 = h2f(wv.y), w2 = h2f(wv.z), w3 = h2f(wv.w);
        acc = fmaf(aA.x, w0.x, acc); acc = fmaf(aA.y, w0.y, acc);
        acc = fmaf(aA.z, w1.x, acc); acc = fmaf(aA.w, w1.y, acc);
        acc = fmaf(aB.x, w2.x, acc); acc = fmaf(aB.y, w2.y, acc);
        acc = fmaf(aB.z, w3.x, acc); acc = fmaf(aB.w, w3.y, acc);
      }
      acc += __shfl_xor(acc, 1);
      acc += __shfl_xor(acc, 2);
      if (kgE == 0) {
        float sg = sigm(gp_c + acc);
        float xv = (iE < 128) ? alpha_s[AIDX(iE)] : pf_c;
        xh_s[iE] = sg * xv;
      }
    }
    __syncthreads();

    // ---- F: gates = WT[512x384]@[xh;h]   [24 coalesced uint4 loads]
    {
      const float* xb = xh_s + kgF * 192;
      float acc = 0.f;
#pragma unroll 8
      for (int i = 0; i < 24; i++) {
        uint4 wv = wtp4[i * 1024 + t];
        float4 xA = *(const float4*)(xb + i * 8);
        float4 xB = *(const float4*)(xb + i * 8 + 4);
        float2 w0 = h2f(wv.x), w1 = h2f(wv.y), w2 = h2f(wv.z), w3 = h2f(wv.w);
        acc = fmaf(xA.x, w0.x, acc); acc = fmaf(xA.y, w0.y, acc);
        acc = fmaf(xA.z, w1.x, acc); acc = fmaf(xA.w, w1.y, acc);
        acc = fmaf(xB.x, w2.x, acc); acc = fmaf(xB.y, w2.y, acc);
        acc = fmaf(xB.z, w3.x, acc); acc = fmaf(xB.w, w3.y, acc);
      }
      acc += __shfl_xor(acc, 1);
      if (kgF == 0) gates_s[iF] = acc + bbF_r;
    }
    __syncthreads();

    // ---- cell: c in regs, h to LDS, out to global
    if (t < 128) {
      float iv = sigm(gates_s[t]);
      float fv = sigm(gates_s[128 + t]);
      float gv = tanh_fast(gates_s[256 + t]);
      float ov = sigm(gates_s[384 + t]);
      float cn = fmaf(fv, c_r, iv * gv);
      float hn = ov * tanh_fast(cn);
      c_r = cn;
      h_s[HIDX(t)] = hn;
      xh_s[256 + t] = hn;
      out[((size_t)b * 128 + st) * 128 + t] = hn;
    }
    __syncthreads();

    wht_c = wht_n; gp_c = gp_n; pf_c = pf_n;
  }
}

// ----------------------------------------------------------------- launcher
extern "C" void kernel_launch(void* const* d_in, const int* in_sizes, int n_in,
                              void* d_out, int out_size, void* d_ws, size_t ws_size,
                              hipStream_t stream) {
  static const int SZ_DICT[18] = {262144, 524288, 16384, 128, 16384, 128,
                                  16384, 128, 128, 1, 65536, 256,
                                  131072, 65536, 512, 512, 2048, 4096};
  static const int ALPHA2DICT[18] = {9, 8, 11, 10, 13, 12, 7, 6, 3, 2, 5, 4,
                                     15, 14, 0, 16, 1, 17};
  const void* in[18];
  for (int i = 0; i < 18; i++) in[i] = (i < n_in) ? d_in[i] : nullptr;

  bool dict_ok = true;
  int lim = (n_in < 16) ? n_in : 16;
  for (int i = 0; i < lim; i++) if (in_sizes[i] != SZ_DICT[i]) dict_ok = false;
  if (!dict_ok) {
    bool alpha_ok = true;
    for (int s = 0; s < n_in && s < 18; s++)
      if (in_sizes[s] != SZ_DICT[ALPHA2DICT[s]]) alpha_ok = false;
    if (alpha_ok)
      for (int s = 0; s < n_in && s < 18; s++) in[ALPHA2DICT[s]] = d_in[s];
  }

  const void* p   = in[0];  const void* q   = in[1];
  const void* Wsw = in[2];  const void* Wsb = in[3];
  const void* Wtw = in[4];  const void* Wtb = in[5];
  const void* Wrw = in[6];  const void* Wrb = in[7];
  const void* Wew = in[8];  const void* Web = in[9];
  const void* Wgw = in[10]; const void* Wgb = in[11];
  const void* Wih = in[12]; const void* Whh = in[13];
  const void* bih = in[14]; const void* bhh = in[15];

  float* ws = (float*)d_ws;
  float* whs  = ws;                          // 524288
  float* pff  = whs + 524288;                // 262144
  float* wht  = pff + 262144;                // 262144
  float* Gp   = wht + 262144;                // 524288
  uint32_t* WrP = (uint32_t*)(Gp + 524288);  // 8192
  uint32_t* WgP = WrP + 8192;                // 16384
  uint32_t* WTP = WgP + 16384;               // 98304
  uint32_t* TAp = WTP + 98304;               // 262144
  float* bbv  = (float*)(TAp + 262144);      // 512
  float* wrb  = bbv + 512;                   // 128
  float* wew  = wrb + 128;                   // 128
  float* web  = wew + 128;                   // 4 (1 used)
  uint32_t* flag = (uint32_t*)(web + 4);     // 4     (~7.8 MB total)

  hipLaunchKernelGGL(detect_kernel, dim3(1), dim3(256), 0, stream,
                     (const uint16_t*)q, flag);
  // 385793 init elements -> 1508 blocks x 256
  hipLaunchKernelGGL(pack2, dim3(1508), dim3(256), 0, stream,
                     p, Wrw, Wrb, Wew, Web, Wgw, Wih, Whh, bih, bhh,
                     pff, WrP, wrb, wew, web, WgP, WTP, bbv, flag);
  hipLaunchKernelGGL(gemm3, dim3(512), dim3(256), 0, stream,
                     q, p, Wsw, Wsb, Wtw, Wtb, Wgw, Wgb, whs, wht, Gp, flag);
  hipLaunchKernelGGL(tapack, dim3(1024), dim3(256), 0, stream, whs, TAp);
  hipLaunchKernelGGL(mlstm_seq9, dim3(16), dim3(1024), 0, stream,
                     pff, whs, wht, Gp, WrP, wrb, wew, web, WgP, WTP, TAp, bbv,
                     (float*)d_out);
}